// Round 9
// baseline (791.296 us; speedup 1.0000x reference)
//
#include <hip/hip_runtime.h>
#include <stdint.h>

#define NUM_CAP 16
#define DIM_CAP 64
#define BATCH   64
#define N_IN    512
#define D_IN    1024
#define N_COL   1024

// ===========================================================================
// Factored capsule routing — u_hat is NEVER materialized.
//   u_hat[b,j,i,k] = sum_d x[b,j,d] W[d,i*64+k]
//   b_ij  = v_i . u_ij  = x[b,j] . wt[b,i]      with wt[b,i,d] = sum_k W[d,ik] v[b,i,k]
//   s_i   = sum_j c_ij u_ij = y[b,i] @ W_i      with y[b,i,d]  = sum_j c_ij x[b,j,d]
//   iter1: c uniform -> s1 = (1/16) * (sum_j x[b,j]) @ W
// All fp32 (matches np reference closely; no bf16 rounding anywhere).
// ===========================================================================

// ---------------------------------------------------------------------------
// k_xsum: xsum4[(b*4+jc)][d] = sum over 128 j of x[b, jc*128+j, d].
// Only kernel that must stream all of x from HBM (128 MB); x stays L3-warm.
// ---------------------------------------------------------------------------
__global__ __launch_bounds__(256) void k_xsum(const float* __restrict__ x,
                                              float* __restrict__ xsum4) {
  const int b = blockIdx.x >> 2, jc = blockIdx.x & 3;
  const int t = threadIdx.x;
  const float* xp = x + ((size_t)(b * 512 + jc * 128)) * 1024 + t * 4;
  float4 a = make_float4(0.f, 0.f, 0.f, 0.f);
  #pragma unroll 4
  for (int j = 0; j < 128; ++j, xp += 1024) {
    const float4 v = *(const float4*)xp;
    a.x += v.x; a.y += v.y; a.z += v.z; a.w += v.w;
  }
  *(float4*)&xsum4[(size_t)blockIdx.x * 1024 + t * 4] = a;
}

// ---------------------------------------------------------------------------
// k_vw: block = (b*16+i), one wave (lane = k).
//  smode 0: s_k = 0.0625 * sum_d xsum[b,d] * W[d, i*64+k]   (routing iter 1)
//  smode 1: s_k = sum_{dc<4} spart[b,dc,i,k]                (iters 2,3)
//  squash: v = s / sqrt(sum_k s^2 + 1e-7)   (wave-reduce over 64 lanes)
//  wmode 1: also emit wt[b,i,d] = sum_k W[d,ik] v_k  (4-d x 16-kq lane split)
//  wmode 0: final -> out[b,i,k] = v
// ---------------------------------------------------------------------------
__global__ __launch_bounds__(64) void k_vw(
    const float* __restrict__ W, const float* __restrict__ xsum4,
    const float* __restrict__ spart, float* __restrict__ wtg,
    float* __restrict__ out, const int smode, const int wmode) {
  __shared__ float xsl[1024];
  __shared__ float vls[64];
  __shared__ float wbuf[1024];
  const int bi = blockIdx.x, b = bi >> 4, i = bi & 15;
  const int lane = threadIdx.x;

  float s;
  if (smode == 0) {
    const float* xs = xsum4 + (size_t)b * 4096;
    #pragma unroll
    for (int it = 0; it < 16; ++it) {
      const int d = it * 64 + lane;
      xsl[d] = xs[d] + xs[1024 + d] + xs[2048 + d] + xs[3072 + d];
    }
    __syncthreads();
    s = 0.f;
    const float* wp = W + i * 64 + lane;
    #pragma unroll 8
    for (int d = 0; d < 1024; ++d)
      s = fmaf(xsl[d], wp[(size_t)d * 1024], s);
    s *= 0.0625f;
  } else {
    const float* sp = spart + (size_t)b * 4096 + i * 64 + lane;
    s = sp[0] + sp[1024] + sp[2048] + sp[3072];
  }

  float ss = s * s;
  #pragma unroll
  for (int d = 1; d < 64; d <<= 1) ss += __shfl_xor(ss, d);
  const float v = s / sqrtf(ss + 1e-7f);

  if (wmode == 0) { out[(size_t)bi * 64 + lane] = v; return; }

  vls[lane] = v;
  __syncthreads();
  const int dq = lane >> 4, kq = lane & 15;
  const float4 vk = *(const float4*)&vls[kq * 4];
  for (int db = 0; db < 1024; db += 4) {
    const int d = db + dq;
    const float4 wr = *(const float4*)&W[(size_t)d * 1024 + i * 64 + kq * 4];
    float p = wr.x * vk.x + wr.y * vk.y + wr.z * vk.z + wr.w * vk.w;
    p += __shfl_xor(p, 1); p += __shfl_xor(p, 2);
    p += __shfl_xor(p, 4); p += __shfl_xor(p, 8);
    if (kq == 0) wbuf[d] = p;
  }
  __syncthreads();
  float* wo = wtg + (size_t)bi * 1024;
  #pragma unroll
  for (int it = 0; it < 16; ++it) wo[it * 64 + lane] = wbuf[it * 64 + lane];
}

// ---------------------------------------------------------------------------
// k_B: b_ij + softmax over i -> c.  Block = (b, jc of 16 j), 256 threads
// (jl = t>>4, i = t&15).  wt[b] (64 KB) staged in LDS with XOR-chunk swizzle
// (float4-chunk c of row i stored at slot c^i -> b128 reads spread 8 bank-
// groups, 2-way = free).  B = x_row . wt_row over d (both d-contiguous).
// Softmax over i = xor-{1,2,4,8} shuffles within the 16-lane i-group.
// cg layout [b][j][i] (i contiguous -> k_ys broadcast reads).
// ---------------------------------------------------------------------------
__global__ __launch_bounds__(256) void k_B(
    const float* __restrict__ x, const float* __restrict__ wtg,
    float* __restrict__ cg) {
  __shared__ float wl[16 * 1024];   // 64 KB
  const int b = blockIdx.x >> 5, jc = blockIdx.x & 31;
  const int t = threadIdx.x, jl = t >> 4, i = t & 15;

  const float4* src = (const float4*)(wtg + (size_t)b * 16384);
  #pragma unroll
  for (int it = 0; it < 16; ++it) {
    const int f4 = it * 256 + t;         // = row it, chunk t
    *(float4*)&wl[it * 1024 + (t ^ it) * 4] = src[f4];
  }
  __syncthreads();

  const int j = jc * 16 + jl;
  const float* xp = x + ((size_t)(b * 512 + j)) * 1024;
  float acc = 0.f;
  #pragma unroll 4
  for (int d = 0; d < 1024; d += 4) {
    const float4 xv = *(const float4*)(xp + d);
    const float4 wv = *(const float4*)&wl[i * 1024 + (((d >> 2)) ^ i) * 4];
    acc = fmaf(xv.x, wv.x, acc); acc = fmaf(xv.y, wv.y, acc);
    acc = fmaf(xv.z, wv.z, acc); acc = fmaf(xv.w, wv.w, acc);
  }
  const float e = __expf(acc);          // |b_ij| <= ~10: no max-subtract needed
  float se = e;
  se += __shfl_xor(se, 1); se += __shfl_xor(se, 2);
  se += __shfl_xor(se, 4); se += __shfl_xor(se, 8);
  cg[(size_t)b * 8192 + jc * 256 + t] = e / se;
}

// ---------------------------------------------------------------------------
// k_ys: y then s-partials.  Block = (b, dc of 256 d), 256 threads.
// Phase 1: thread owns d = dc*256+t, 16 i-accums: y[i,d] = sum_j c[j,i]*x[j,d]
//   (c rows broadcast from LDS, x loads coalesced 1 KB/instr).
// Phase 2: y -> LDS (stride 260: 2-way banks).
// Phase 3: threads re-split (i = t>>4, kq = t&15):
//   spart[b,dc,i,kq*4..+3] = sum_dl y[i,dl] * W[dc*256+dl, i*64+kq*4..+3].
// ---------------------------------------------------------------------------
__global__ __launch_bounds__(256) void k_ys(
    const float* __restrict__ x, const float* __restrict__ cg,
    const float* __restrict__ W, float* __restrict__ spart) {
  __shared__ float cl[512 * 16];    // 32 KB
  __shared__ float yl[16 * 260];    // 16.6 KB
  const int b = blockIdx.x >> 2, dc = blockIdx.x & 3;
  const int t = threadIdx.x;

  const float4* csrc = (const float4*)(cg + (size_t)b * 8192);
  #pragma unroll
  for (int it = 0; it < 8; ++it)
    *(float4*)&cl[(it * 256 + t) * 4] = csrc[it * 256 + t];
  __syncthreads();

  float acc[16];
  #pragma unroll
  for (int q = 0; q < 16; ++q) acc[q] = 0.f;
  const float* xp = x + (size_t)b * 512 * 1024 + dc * 256 + t;
  #pragma unroll 2
  for (int j = 0; j < 512; ++j) {
    const float xv = xp[(size_t)j * 1024];
    const float4 c0 = *(const float4*)&cl[j * 16];
    const float4 c1 = *(const float4*)&cl[j * 16 + 4];
    const float4 c2 = *(const float4*)&cl[j * 16 + 8];
    const float4 c3 = *(const float4*)&cl[j * 16 + 12];
    acc[0]  = fmaf(c0.x, xv, acc[0]);  acc[1]  = fmaf(c0.y, xv, acc[1]);
    acc[2]  = fmaf(c0.z, xv, acc[2]);  acc[3]  = fmaf(c0.w, xv, acc[3]);
    acc[4]  = fmaf(c1.x, xv, acc[4]);  acc[5]  = fmaf(c1.y, xv, acc[5]);
    acc[6]  = fmaf(c1.z, xv, acc[6]);  acc[7]  = fmaf(c1.w, xv, acc[7]);
    acc[8]  = fmaf(c2.x, xv, acc[8]);  acc[9]  = fmaf(c2.y, xv, acc[9]);
    acc[10] = fmaf(c2.z, xv, acc[10]); acc[11] = fmaf(c2.w, xv, acc[11]);
    acc[12] = fmaf(c3.x, xv, acc[12]); acc[13] = fmaf(c3.y, xv, acc[13]);
    acc[14] = fmaf(c3.z, xv, acc[14]); acc[15] = fmaf(c3.w, xv, acc[15]);
  }
  #pragma unroll
  for (int q = 0; q < 16; ++q) yl[q * 260 + t] = acc[q];
  __syncthreads();

  const int i = t >> 4, kq = t & 15;
  float4 sa = make_float4(0.f, 0.f, 0.f, 0.f);
  const float* wp = W + (size_t)(dc * 256) * 1024 + i * 64 + kq * 4;
  #pragma unroll 4
  for (int dl = 0; dl < 256; ++dl) {
    const float yv = yl[i * 260 + dl];
    const float4 wv = *(const float4*)(wp + (size_t)dl * 1024);
    sa.x = fmaf(yv, wv.x, sa.x); sa.y = fmaf(yv, wv.y, sa.y);
    sa.z = fmaf(yv, wv.z, sa.z); sa.w = fmaf(yv, wv.w, sa.w);
  }
  *(float4*)&spart[((size_t)b * 4 + dc) * 1024 + i * 64 + kq * 4] = sa;
}

// ---------------------------------------------------------------------------
extern "C" void kernel_launch(void* const* d_in, const int* in_sizes, int n_in,
                              void* d_out, int out_size, void* d_ws, size_t ws_size,
                              hipStream_t stream) {
  const float* x = (const float*)d_in[0];   // [64][512][1024] fp32
  const float* W = (const float*)d_in[1];   // [1][1024][1024] fp32
  float* out = (float*)d_out;               // [64][16][64] fp32

  char* ws = (char*)d_ws;
  float* xsum4 = (float*)ws;                             // 1 MB
  float* wtg   = (float*)(ws + (size_t)2  * (1 << 20));  // 4 MB  [b][i][d]
  float* cg    = (float*)(ws + (size_t)8  * (1 << 20));  // 2 MB  [b][j][i]
  float* spart = (float*)(ws + (size_t)12 * (1 << 20));  // 1 MB  [b][dc][i][k]

  k_xsum<<<256, 256, 0, stream>>>(x, xsum4);
  // iter 1: v1 from xsum, emit wt1
  k_vw<<<1024, 64, 0, stream>>>(W, xsum4, spart, wtg, out, 0, 1);
  // iter 2
  k_B <<<2048, 256, 0, stream>>>(x, wtg, cg);
  k_ys<<<256, 256, 0, stream>>>(x, cg, W, spart);
  k_vw<<<1024, 64, 0, stream>>>(W, xsum4, spart, wtg, out, 1, 1);
  // iter 3
  k_B <<<2048, 256, 0, stream>>>(x, wtg, cg);
  k_ys<<<256, 256, 0, stream>>>(x, cg, W, spart);
  k_vw<<<1024, 64, 0, stream>>>(W, xsum4, spart, wtg, out, 1, 0);  // -> out
}

// Round 10
// 335.925 us; speedup vs baseline: 2.3556x; 2.3556x over previous
//
#include <hip/hip_runtime.h>
#include <stdint.h>

#define NUM_CAP 16
#define DIM_CAP 64
#define BATCH   64
#define N_IN    512
#define D_IN    1024
#define N_COL   1024
#define M_ROWS  (BATCH*N_IN)

typedef __attribute__((ext_vector_type(8))) short short8;
typedef __attribute__((ext_vector_type(4))) float f32x4;

__device__ __forceinline__ float bf2f(unsigned int u) {
  return __uint_as_float(u << 16);
}
__device__ __forceinline__ unsigned short f2bf_rne(float f) {
  unsigned int x = __float_as_uint(f);
  x += 0x7fffu + ((x >> 16) & 1u);
  return (unsigned short)(x >> 16);
}
__device__ __forceinline__ unsigned int pack_rne(unsigned int lo, unsigned int hi) {
  const unsigned int lr = lo + (0x7fffu + ((lo >> 16) & 1u));
  const unsigned int hr = hi + (0x7fffu + ((hi >> 16) & 1u));
  return (lr >> 16) | (hr & 0xffff0000u);
}

// ---------------------------------------------------------------------------
// prep: blocks [0,16384) convert x fp32->bf16 (R7-proven); blocks
// [16384,17408) transpose+convert W -> Wt[n][k].  (R7's fused prep kernel.)
// ---------------------------------------------------------------------------
__global__ __launch_bounds__(256) void prep(
    const float* __restrict__ x, const float* __restrict__ W,
    unsigned short* __restrict__ xb, unsigned short* __restrict__ Wt) {
  const int t = threadIdx.x;
  if (blockIdx.x < 16384) {
    const size_t i = ((size_t)blockIdx.x * 256 + t) * 8;
    const uint4 a = *(const uint4*)(x + i);
    const uint4 b = *(const uint4*)(x + i + 4);
    uint4 p;
    p.x = pack_rne(a.x, a.y); p.y = pack_rne(a.z, a.w);
    p.z = pack_rne(b.x, b.y); p.w = pack_rne(b.z, b.w);
    *(uint4*)(xb + i) = p;
  } else {
    __shared__ float tile[32][33];
    const int bid = blockIdx.x - 16384;
    const int bx = bid & 31, by = bid >> 5;
    const int tx = t & 31, ty0 = t >> 5;
    #pragma unroll
    for (int r = 0; r < 4; r++) {
      const int ty = ty0 + r * 8;
      tile[ty][tx] = W[(size_t)(by * 32 + ty) * N_COL + bx * 32 + tx];
    }
    __syncthreads();
    #pragma unroll
    for (int r = 0; r < 4; r++) {
      const int ty = ty0 + r * 8;
      Wt[(size_t)(bx * 32 + ty) * D_IN + by * 32 + tx] = f2bf_rne(tile[tx][ty]);
    }
  }
}

// ---------------------------------------------------------------------------
// GEMM — R7-measured K-loop (91 us, VGPR 72, conflicts 0, FETCH 57 MB),
// byte-identical: bf16 operands via global_load_lds w=16, XOR-swizzled LDS,
// XCD map.  Epilogue adds Pp[mt][n] = column sums of the block's 128 rows
// (routing iter-1 partials, scale-free): shuffles + 1 KB LDS + disjoint
// stores, NO atomics (R6's cost was atomics/VGPR; R8's was the fp32-A loop).
// ---------------------------------------------------------------------------
__global__ __launch_bounds__(256) void gemm_uhat(
    const unsigned short* __restrict__ A,
    const unsigned short* __restrict__ Bt,
    unsigned short* __restrict__ C,
    float* __restrict__ Pp) {
  __shared__ __align__(16) unsigned short lA[128 * 32];
  __shared__ __align__(16) unsigned short lB[128 * 32];
  __shared__ float cs2[2][128];

  const int t = threadIdx.x;
  const int wave = t >> 6, lane = t & 63;
  const int xcd = blockIdx.x & 7, local = blockIdx.x >> 3;
  const int mt = xcd * 32 + (local >> 3), nt = local & 7;
  const int m0 = mt * 128, n0 = nt * 128;
  const int wm = wave & 1, wn = wave >> 1;

  f32x4 acc[4][4] = {};

  const int srow = lane >> 2;
  const int schunk = ((lane & 3) ^ ((srow >> 1) & 3)) * 8;

  for (int kt = 0; kt < D_IN / 32; ++kt) {
    const int k0 = kt * 32;
    __syncthreads();
    #pragma unroll
    for (int s0 = 0; s0 < 2; ++s0) {
      const int s = wave + s0 * 4;
      const unsigned short* ga = A + (size_t)(m0 + s * 16 + srow) * D_IN + k0 + schunk;
      __builtin_amdgcn_global_load_lds(
          (const __attribute__((address_space(1))) void*)ga,
          (__attribute__((address_space(3))) void*)(lA + s * 512), 16, 0, 0);
      const unsigned short* gb = Bt + (size_t)(n0 + s * 16 + srow) * D_IN + k0 + schunk;
      __builtin_amdgcn_global_load_lds(
          (const __attribute__((address_space(1))) void*)gb,
          (__attribute__((address_space(3))) void*)(lB + s * 512), 16, 0, 0);
    }
    __syncthreads();

    short8 af[4], bfr[4];
    const int rsel = lane & 15;
    const int q = lane >> 4;
    const int koff = (q ^ ((rsel >> 1) & 3)) * 8;
    #pragma unroll
    for (int tm = 0; tm < 4; tm++)
      af[tm] = *(const short8*)&lA[(wm * 64 + tm * 16 + rsel) * 32 + koff];
    #pragma unroll
    for (int tn = 0; tn < 4; tn++)
      bfr[tn] = *(const short8*)&lB[(wn * 64 + tn * 16 + rsel) * 32 + koff];
    #pragma unroll
    for (int tm = 0; tm < 4; tm++)
      #pragma unroll
      for (int tn = 0; tn < 4; tn++)
        acc[tm][tn] = __builtin_amdgcn_mfma_f32_16x16x32_bf16(
            af[tm], bfr[tn], acc[tm][tn], 0, 0, 0);
  }

  const int lrow = (lane >> 4) * 4, lcol = lane & 15;
  #pragma unroll
  for (int tm = 0; tm < 4; tm++)
    #pragma unroll
    for (int tn = 0; tn < 4; tn++)
      #pragma unroll
      for (int r = 0; r < 4; r++) {
        const int row = m0 + wm * 64 + tm * 16 + lrow + r;
        const int col = n0 + wn * 64 + tn * 16 + lcol;
        C[(size_t)row * N_COL + col] = f2bf_rne(acc[tm][tn][r]);
      }

  #pragma unroll
  for (int tn = 0; tn < 4; tn++) {
    float p = 0.f;
    #pragma unroll
    for (int tm = 0; tm < 4; tm++)
      #pragma unroll
      for (int r = 0; r < 4; r++) p += acc[tm][tn][r];
    p += __shfl_xor(p, 16);
    p += __shfl_xor(p, 32);
    if (lane < 16) cs2[wm][wn * 64 + tn * 16 + lane] = p;
  }
  __syncthreads();
  if (t < 128)
    Pp[(size_t)mt * N_COL + n0 + t] = cs2[0][t] + cs2[1][t];
}

// ---------------------------------------------------------------------------
// k_v: sum nstrips strips -> s[b][1024]; squash per capsule (16-lane groups);
// write v[b][1024] (also the final out layout).  64 blocks x 256 threads.
// ---------------------------------------------------------------------------
__global__ __launch_bounds__(256) void k_v(
    const float* __restrict__ Pin, float* __restrict__ vout, const int nstrips) {
  const int b = blockIdx.x, t = threadIdx.x;
  float4 s = make_float4(0.f, 0.f, 0.f, 0.f);
  for (int q = 0; q < nstrips; ++q) {
    const float4 p = *(const float4*)&Pin[((size_t)b * nstrips + q) * 1024 + t * 4];
    s.x += p.x; s.y += p.y; s.z += p.z; s.w += p.w;
  }
  float ss = s.x * s.x + s.y * s.y + s.z * s.z + s.w * s.w;
  #pragma unroll
  for (int d = 1; d < 16; d <<= 1) ss += __shfl_xor(ss, d);
  const float inv = 1.f / sqrtf(ss + 1e-7f);
  *(float4*)&vout[(size_t)b * 1024 + t * 4] =
      make_float4(s.x * inv, s.y * inv, s.z * inv, s.w * inv);
}

// ---------------------------------------------------------------------------
// route_mid: block=(b, jt of 32), 4 waves, wave handles 4 j's with a 2-deep
// register pipeline.  2048 blocks -> ~2x the TLP of R7's version (whose
// ~45 us/pass was one cold-load stall per short-lived wave).  v[b] comes from
// a 4 KB global read (k_v hoisted the strip reduce+squash out of this grid).
// ---------------------------------------------------------------------------
__global__ __launch_bounds__(256) void route_mid(
    const unsigned short* __restrict__ uhat,
    const float* __restrict__ v,
    float* __restrict__ Pout) {
  __shared__ float sq[16 * 68];
  __shared__ float red[4][1024];
  const int t = threadIdx.x;
  const int w = t >> 6, lane = t & 63;
  const int b = blockIdx.x >> 5, jt = blockIdx.x & 31;
  const int i_l = lane >> 2, c4 = lane & 3;

  {
    const float4 vv = *(const float4*)&v[(size_t)b * 1024 + t * 4];
    *(float4*)&sq[(t >> 4) * 68 + (t & 15) * 4] = vv;
  }
  __syncthreads();

  float pv[16];
  #pragma unroll
  for (int q = 0; q < 4; q++)
    *(float4*)&pv[q * 4] = *(const float4*)&sq[i_l * 68 + c4 * 16 + q * 4];

  float acc[16];
  #pragma unroll
  for (int q = 0; q < 16; q++) acc[q] = 0.f;

  const unsigned short* ub =
      uhat + (size_t)(b * N_IN + jt * 16 + w * 4) * N_COL + lane * 16;

  uint4 c0 = *(const uint4*)ub;
  uint4 c1 = *(const uint4*)(ub + 8);
  #pragma unroll
  for (int jj = 0; jj < 4; ++jj) {
    uint4 n0v = c0, n1v = c1;
    if (jj < 3) {
      n0v = *(const uint4*)(ub + N_COL);
      n1v = *(const uint4*)(ub + N_COL + 8);
    }
    float u[16];
    #define UNP(wd, o) { u[(o)] = bf2f((wd) & 0xffffu); u[(o)+1] = __uint_as_float((wd) & 0xffff0000u); }
    UNP(c0.x, 0) UNP(c0.y, 2) UNP(c0.z, 4) UNP(c0.w, 6)
    UNP(c1.x, 8) UNP(c1.y, 10) UNP(c1.z, 12) UNP(c1.w, 14)
    #undef UNP

    float dot = 0.f;
    #pragma unroll
    for (int q = 0; q < 16; q++) dot = fmaf(pv[q], u[q], dot);
    dot += __shfl_xor(dot, 1);
    dot += __shfl_xor(dot, 2);
    const float e = __expf(dot);
    float s = e;
    #pragma unroll
    for (int d = 4; d < 64; d <<= 1) s += __shfl_xor(s, d);
    const float c = e / s;
    #pragma unroll
    for (int q = 0; q < 16; q++) acc[q] = fmaf(c, u[q], acc[q]);

    c0 = n0v; c1 = n1v; ub += N_COL;
  }

  #pragma unroll
  for (int q = 0; q < 4; q++)
    *(float4*)&red[w][lane * 16 + q * 4] = make_float4(
        acc[q * 4 + 0], acc[q * 4 + 1], acc[q * 4 + 2], acc[q * 4 + 3]);
  __syncthreads();
  float4 s4 = make_float4(0.f, 0.f, 0.f, 0.f);
  #pragma unroll
  for (int ww = 0; ww < 4; ++ww) {
    const float4 r = *(const float4*)&red[ww][t * 4];
    s4.x += r.x; s4.y += r.y; s4.z += r.z; s4.w += r.w;
  }
  *(float4*)&Pout[(size_t)blockIdx.x * 1024 + t * 4] = s4;
}

// ---------------------------------------------------------------------------
extern "C" void kernel_launch(void* const* d_in, const int* in_sizes, int n_in,
                              void* d_out, int out_size, void* d_ws, size_t ws_size,
                              hipStream_t stream) {
  const float* x = (const float*)d_in[0];   // [64][512][1024] fp32
  const float* W = (const float*)d_in[1];   // [1][1024][1024] fp32
  float* out = (float*)d_out;               // [64][16][64] fp32

  char* ws = (char*)d_ws;
  unsigned short* Wt   = (unsigned short*)ws;                            // 0..2 MB
  unsigned short* uhat = (unsigned short*)(ws + (size_t)(2 << 20));      // 2..66 MB
  float* Pp = (float*)(ws + (size_t)66 * (1 << 20));                     // 66..67 MB
  float* v1 = (float*)(ws + (size_t)67 * (1 << 20));                     // 67..67.25
  float* v2 = (float*)(ws + (size_t)67 * (1 << 20) + (512 << 10));       // 67.5..67.75
  unsigned short* xb = (unsigned short*)(ws + (size_t)68 * (1 << 20));   // 68..132 (dead after gemm)
  float* P1 = (float*)(ws + (size_t)68 * (1 << 20));   // reuses dead xb: 68..76
  float* P2 = (float*)(ws + (size_t)76 * (1 << 20));   // reuses dead xb: 76..84

  prep<<<16384 + 1024, 256, 0, stream>>>(x, W, xb, Wt);
  gemm_uhat<<<2048, 256, 0, stream>>>(xb, Wt, uhat, Pp);
  k_v<<<64, 256, 0, stream>>>(Pp, v1, 4);
  route_mid<<<2048, 256, 0, stream>>>(uhat, v1, P1);
  k_v<<<64, 256, 0, stream>>>(P1, v2, 32);
  route_mid<<<2048, 256, 0, stream>>>(uhat, v2, P2);
  k_v<<<64, 256, 0, stream>>>(P2, out, 32);
}

// Round 11
// 335.229 us; speedup vs baseline: 2.3605x; 1.0021x over previous
//
#include <hip/hip_runtime.h>
#include <stdint.h>

#define NUM_CAP 16
#define DIM_CAP 64
#define BATCH   64
#define N_IN    512
#define D_IN    1024
#define N_COL   1024
#define M_ROWS  (BATCH*N_IN)

typedef __attribute__((ext_vector_type(8))) short short8;
typedef __attribute__((ext_vector_type(4))) float f32x4;

__device__ __forceinline__ float bf2f(unsigned int u) {
  return __uint_as_float(u << 16);
}
__device__ __forceinline__ unsigned short f2bf_rne(float f) {
  unsigned int x = __float_as_uint(f);
  x += 0x7fffu + ((x >> 16) & 1u);
  return (unsigned short)(x >> 16);
}
__device__ __forceinline__ unsigned int pack_rne(unsigned int lo, unsigned int hi) {
  const unsigned int lr = lo + (0x7fffu + ((lo >> 16) & 1u));
  const unsigned int hr = hi + (0x7fffu + ((hi >> 16) & 1u));
  return (lr >> 16) | (hr & 0xffff0000u);
}

// ---------------------------------------------------------------------------
// prep (R7/R10-proven): blocks [0,16384) convert x fp32->bf16; blocks
// [16384,17408) transpose+convert W -> Wt[n][k].
// ---------------------------------------------------------------------------
__global__ __launch_bounds__(256) void prep(
    const float* __restrict__ x, const float* __restrict__ W,
    unsigned short* __restrict__ xb, unsigned short* __restrict__ Wt) {
  const int t = threadIdx.x;
  if (blockIdx.x < 16384) {
    const size_t i = ((size_t)blockIdx.x * 256 + t) * 8;
    const uint4 a = *(const uint4*)(x + i);
    const uint4 b = *(const uint4*)(x + i + 4);
    uint4 p;
    p.x = pack_rne(a.x, a.y); p.y = pack_rne(a.z, a.w);
    p.z = pack_rne(b.x, b.y); p.w = pack_rne(b.z, b.w);
    *(uint4*)(xb + i) = p;
  } else {
    __shared__ float tile[32][33];
    const int bid = blockIdx.x - 16384;
    const int bx = bid & 31, by = bid >> 5;
    const int tx = t & 31, ty0 = t >> 5;
    #pragma unroll
    for (int r = 0; r < 4; r++) {
      const int ty = ty0 + r * 8;
      tile[ty][tx] = W[(size_t)(by * 32 + ty) * N_COL + bx * 32 + tx];
    }
    __syncthreads();
    #pragma unroll
    for (int r = 0; r < 4; r++) {
      const int ty = ty0 + r * 8;
      Wt[(size_t)(bx * 32 + ty) * D_IN + by * 32 + tx] = f2bf_rne(tile[tx][ty]);
    }
  }
}

// ---------------------------------------------------------------------------
// GEMM (R10-measured, 105 us): R7 K-loop (bf16 global_load_lds w=16, XOR-
// swizzled LDS, conflicts 0, XCD map) + Pp column-sum epilogue (replaces the
// 50-us s1q full-uhat pass for +14 us of gemm; net win per R7/R10 ledger).
// ---------------------------------------------------------------------------
__global__ __launch_bounds__(256) void gemm_uhat(
    const unsigned short* __restrict__ A,
    const unsigned short* __restrict__ Bt,
    unsigned short* __restrict__ C,
    float* __restrict__ Pp) {
  __shared__ __align__(16) unsigned short lA[128 * 32];
  __shared__ __align__(16) unsigned short lB[128 * 32];
  __shared__ float cs2[2][128];

  const int t = threadIdx.x;
  const int wave = t >> 6, lane = t & 63;
  const int xcd = blockIdx.x & 7, local = blockIdx.x >> 3;
  const int mt = xcd * 32 + (local >> 3), nt = local & 7;
  const int m0 = mt * 128, n0 = nt * 128;
  const int wm = wave & 1, wn = wave >> 1;

  f32x4 acc[4][4] = {};

  const int srow = lane >> 2;
  const int schunk = ((lane & 3) ^ ((srow >> 1) & 3)) * 8;

  for (int kt = 0; kt < D_IN / 32; ++kt) {
    const int k0 = kt * 32;
    __syncthreads();
    #pragma unroll
    for (int s0 = 0; s0 < 2; ++s0) {
      const int s = wave + s0 * 4;
      const unsigned short* ga = A + (size_t)(m0 + s * 16 + srow) * D_IN + k0 + schunk;
      __builtin_amdgcn_global_load_lds(
          (const __attribute__((address_space(1))) void*)ga,
          (__attribute__((address_space(3))) void*)(lA + s * 512), 16, 0, 0);
      const unsigned short* gb = Bt + (size_t)(n0 + s * 16 + srow) * D_IN + k0 + schunk;
      __builtin_amdgcn_global_load_lds(
          (const __attribute__((address_space(1))) void*)gb,
          (__attribute__((address_space(3))) void*)(lB + s * 512), 16, 0, 0);
    }
    __syncthreads();

    short8 af[4], bfr[4];
    const int rsel = lane & 15;
    const int q = lane >> 4;
    const int koff = (q ^ ((rsel >> 1) & 3)) * 8;
    #pragma unroll
    for (int tm = 0; tm < 4; tm++)
      af[tm] = *(const short8*)&lA[(wm * 64 + tm * 16 + rsel) * 32 + koff];
    #pragma unroll
    for (int tn = 0; tn < 4; tn++)
      bfr[tn] = *(const short8*)&lB[(wn * 64 + tn * 16 + rsel) * 32 + koff];
    #pragma unroll
    for (int tm = 0; tm < 4; tm++)
      #pragma unroll
      for (int tn = 0; tn < 4; tn++)
        acc[tm][tn] = __builtin_amdgcn_mfma_f32_16x16x32_bf16(
            af[tm], bfr[tn], acc[tm][tn], 0, 0, 0);
  }

  const int lrow = (lane >> 4) * 4, lcol = lane & 15;
  #pragma unroll
  for (int tm = 0; tm < 4; tm++)
    #pragma unroll
    for (int tn = 0; tn < 4; tn++)
      #pragma unroll
      for (int r = 0; r < 4; r++) {
        const int row = m0 + wm * 64 + tm * 16 + lrow + r;
        const int col = n0 + wn * 64 + tn * 16 + lcol;
        C[(size_t)row * N_COL + col] = f2bf_rne(acc[tm][tn][r]);
      }

  #pragma unroll
  for (int tn = 0; tn < 4; tn++) {
    float p = 0.f;
    #pragma unroll
    for (int tm = 0; tm < 4; tm++)
      #pragma unroll
      for (int r = 0; r < 4; r++) p += acc[tm][tn][r];
    p += __shfl_xor(p, 16);
    p += __shfl_xor(p, 32);
    if (lane < 16) cs2[wm][wn * 64 + tn * 16 + lane] = p;
  }
  __syncthreads();
  if (t < 128)
    Pp[(size_t)mt * N_COL + n0 + t] = cs2[0][t] + cs2[1][t];
}

// ---------------------------------------------------------------------------
// route_mid v3: block = task tid = b*32+jt, mapped so blockIdx&7 == b>>3
// (gemm's XCD map leaves b's uhat rows in XCD b>>3's L2 -> local reads).
// Phase A (in-kernel, redundant; strip set <=8 MB hot): sum nstrips strips of
// Vin -> s[b], squash -> v -> LDS.  Phase B: wave w handles 4 j's with ALL
// 8 b128 loads issued before the softmax chain consumes any (4-deep MLP);
// softmax over i via shuffles; 4-wave LDS reduce -> Pout[tid][i*64+k].
// ---------------------------------------------------------------------------
__global__ __launch_bounds__(256) void route_mid(
    const unsigned short* __restrict__ uhat,
    const float* __restrict__ Vin,
    float* __restrict__ Pout,
    const int nstrips) {
  __shared__ float sq[16 * 68];
  __shared__ float red[4][1024];
  const int t = threadIdx.x;
  const int w = t >> 6, lane = t & 63;
  const int xcd = blockIdx.x & 7, kk = blockIdx.x >> 3;
  const int b = xcd * 8 + (kk >> 5), jt = kk & 31;
  const int tid = b * 32 + jt;
  const int i_l = lane >> 2, c4 = lane & 3;

  // ---- phase A: strip reduce + squash
  float4 v4 = make_float4(0.f, 0.f, 0.f, 0.f);
  for (int s = 0; s < nstrips; ++s) {
    const float4 ps = *(const float4*)&Vin[((size_t)b * nstrips + s) * 1024 + t * 4];
    v4.x += ps.x; v4.y += ps.y; v4.z += ps.z; v4.w += ps.w;
  }
  float ss = v4.x * v4.x + v4.y * v4.y + v4.z * v4.z + v4.w * v4.w;
  #pragma unroll
  for (int d = 1; d < 16; d <<= 1) ss += __shfl_xor(ss, d);  // 16 lanes = one capsule
  const float inv = 1.f / sqrtf(ss + 1e-7f);
  *(float4*)&sq[(t >> 4) * 68 + (t & 15) * 4] =
      make_float4(v4.x * inv, v4.y * inv, v4.z * inv, v4.w * inv);
  __syncthreads();

  float pv[16];
  #pragma unroll
  for (int q = 0; q < 4; q++)
    *(float4*)&pv[q * 4] = *(const float4*)&sq[i_l * 68 + c4 * 16 + q * 4];

  // ---- phase B: 4 j per wave, loads 4-deep
  float acc[16];
  #pragma unroll
  for (int q = 0; q < 16; q++) acc[q] = 0.f;

  const unsigned short* ub =
      uhat + (size_t)(b * N_IN + jt * 16 + w * 4) * N_COL + lane * 16;

  uint4 d0[4], d1[4];
  #pragma unroll
  for (int jj = 0; jj < 4; ++jj) {
    d0[jj] = *(const uint4*)(ub + (size_t)jj * N_COL);
    d1[jj] = *(const uint4*)(ub + (size_t)jj * N_COL + 8);
  }

  #pragma unroll
  for (int jj = 0; jj < 4; ++jj) {
    float u[16];
    #define UNP(wd, o) { u[(o)] = bf2f((wd) & 0xffffu); u[(o)+1] = __uint_as_float((wd) & 0xffff0000u); }
    UNP(d0[jj].x, 0) UNP(d0[jj].y, 2) UNP(d0[jj].z, 4) UNP(d0[jj].w, 6)
    UNP(d1[jj].x, 8) UNP(d1[jj].y, 10) UNP(d1[jj].z, 12) UNP(d1[jj].w, 14)
    #undef UNP

    float dot = 0.f;
    #pragma unroll
    for (int q = 0; q < 16; q++) dot = fmaf(pv[q], u[q], dot);
    dot += __shfl_xor(dot, 1);     // quad-reduce over k -> b_i
    dot += __shfl_xor(dot, 2);
    const float e = __expf(dot);   // |b| bounded -> no max-subtract
    float s = e;
    #pragma unroll
    for (int d = 4; d < 64; d <<= 1) s += __shfl_xor(s, d);
    const float c = e / s;
    #pragma unroll
    for (int q = 0; q < 16; q++) acc[q] = fmaf(c, u[q], acc[q]);
  }

  #pragma unroll
  for (int q = 0; q < 4; q++)
    *(float4*)&red[w][lane * 16 + q * 4] = make_float4(
        acc[q * 4 + 0], acc[q * 4 + 1], acc[q * 4 + 2], acc[q * 4 + 3]);
  __syncthreads();
  float4 s4 = make_float4(0.f, 0.f, 0.f, 0.f);
  #pragma unroll
  for (int ww = 0; ww < 4; ++ww) {
    const float4 r = *(const float4*)&red[ww][t * 4];
    s4.x += r.x; s4.y += r.y; s4.z += r.z; s4.w += r.w;
  }
  *(float4*)&Pout[(size_t)tid * 1024 + t * 4] = s4;
}

// ---------------------------------------------------------------------------
// k_out: final strip reduce + squash -> out.  256 blocks = (b, ic of 4),
// thread (il = t>>6, k = t&63); wave == one capsule -> full-wave ss reduce.
// ---------------------------------------------------------------------------
__global__ __launch_bounds__(256) void k_out(
    const float* __restrict__ P, float* __restrict__ out) {
  const int b = blockIdx.x >> 2, ic = blockIdx.x & 3;
  const int t = threadIdx.x;
  const int i = ic * 4 + (t >> 6), k = t & 63;
  const float* p = P + (size_t)b * 32 * 1024 + i * 64 + k;
  float s = 0.f;
  #pragma unroll
  for (int q = 0; q < 32; ++q) s += p[(size_t)q * 1024];
  float ss = s * s;
  #pragma unroll
  for (int d = 1; d < 64; d <<= 1) ss += __shfl_xor(ss, d);
  out[((size_t)b * 16 + i) * 64 + k] = s / sqrtf(ss + 1e-7f);
}

// ---------------------------------------------------------------------------
extern "C" void kernel_launch(void* const* d_in, const int* in_sizes, int n_in,
                              void* d_out, int out_size, void* d_ws, size_t ws_size,
                              hipStream_t stream) {
  const float* x = (const float*)d_in[0];   // [64][512][1024] fp32
  const float* W = (const float*)d_in[1];   // [1][1024][1024] fp32
  float* out = (float*)d_out;               // [64][16][64] fp32

  char* ws = (char*)d_ws;
  unsigned short* Wt   = (unsigned short*)ws;                            // 0..2 MB
  unsigned short* uhat = (unsigned short*)(ws + (size_t)(2 << 20));      // 2..66 MB
  float* Pp = (float*)(ws + (size_t)66 * (1 << 20));                     // 66..67 MB
  unsigned short* xb = (unsigned short*)(ws + (size_t)68 * (1 << 20));   // 68..132 (dead after gemm)
  float* P1 = (float*)(ws + (size_t)68 * (1 << 20));   // reuses dead xb: 68..76
  float* P2 = (float*)(ws + (size_t)76 * (1 << 20));   // reuses dead xb: 76..84

  prep<<<16384 + 1024, 256, 0, stream>>>(x, W, xb, Wt);
  gemm_uhat<<<2048, 256, 0, stream>>>(xb, Wt, uhat, Pp);
  route_mid<<<2048, 256, 0, stream>>>(uhat, Pp, P1, 4);   // routing iter 2
  route_mid<<<2048, 256, 0, stream>>>(uhat, P1, P2, 32);  // routing iter 3
  k_out<<<256, 256, 0, stream>>>(P2, out);
}